// Round 1
// baseline (418.498 us; speedup 1.0000x reference)
//
#include <hip/hip_runtime.h>
#include <cstddef>

// Problem constants (from reference setup_inputs):
//   x      [4, 256, 64, 64] fp32
//   offset [4, 18, 64, 64]  fp32   (dy,dx) pairs per 3x3 tap
//   weight [256, 256, 3, 3] fp32
//   out    [4, 256, 64, 64] fp32
// stride=1, pad=1, dil=1 -> Ho=Wo=64
#define B_    4
#define C_    256
#define H_    64
#define W_    64
#define CO_   256
#define K2_   9
#define HOWO_ 64   // one output row per block (wo = 0..63)

// ---------------------------------------------------------------------------
// weight [Co][C][9] -> wT [9][C][Co]  (so the main kernel's weight loads are
// lane-coalesced in o)
// ---------------------------------------------------------------------------
__global__ void wtrans_kernel(const float* __restrict__ w, float* __restrict__ wT) {
    int i = blockIdx.x * 256 + threadIdx.x;          // 9*256*256 = 589824
    if (i >= K2_ * C_ * CO_) return;
    int o = i & 255;
    int c = (i >> 8) & 255;
    int k = i >> 16;                                  // C_*CO_ = 65536
    wT[i] = w[(o * C_ + c) * K2_ + k];
}

// ---------------------------------------------------------------------------
// Fused deformable conv: one block per (b, ho). 512 threads.
// Thread tile: 2 output channels x 16 output columns (acc = float4[2][4]).
// ---------------------------------------------------------------------------
__global__ __launch_bounds__(512, 1)
void dcn_fwd_kernel(const float* __restrict__ x,
                    const float* __restrict__ off,
                    const float* __restrict__ wsrc,   // wT if use_wt else weight
                    float* __restrict__ out,
                    int use_wt) {
    __shared__ float s_w[4][K2_][HOWO_];   // corner weights (validity folded in)
    __shared__ int   s_idx[4][K2_][HOWO_]; // clamped within-plane indices
    __shared__ float s_col[32][HOWO_];     // bilinear-sampled col chunk

    const int tid = threadIdx.x;
    const int b  = blockIdx.x >> 6;
    const int ho = blockIdx.x & 63;

    // ---- Phase 1: sampling metadata for 9 taps x 64 output columns --------
    for (int e = tid; e < K2_ * HOWO_; e += 512) {
        const int k = e >> 6;       // tap
        const int p = e & 63;       // wo
        const float dy = off[((b * 18 + 2 * k    ) * 64 + ho) * 64 + p];
        const float dx = off[((b * 18 + 2 * k + 1) * 64 + ho) * 64 + p];
        const float py = (float)(ho - 1 + k / 3) + dy;
        const float px = (float)(p  - 1 + k % 3) + dx;
        const float y0f = floorf(py);
        const float x0f = floorf(px);
        const float ly = py - y0f, lx = px - x0f;
        const float hy = 1.0f - ly, hx = 1.0f - lx;
        const int y0 = (int)y0f, x0 = (int)x0f;
        const int y1 = y0 + 1,   x1 = x0 + 1;
        const bool vy0 = (y0 >= 0) & (y0 < H_);
        const bool vy1 = (y1 >= 0) & (y1 < H_);
        const bool vx0 = (x0 >= 0) & (x0 < W_);
        const bool vx1 = (x1 >= 0) & (x1 < W_);
        const int yc0 = min(max(y0, 0), H_ - 1);
        const int yc1 = min(max(y1, 0), H_ - 1);
        const int xc0 = min(max(x0, 0), W_ - 1);
        const int xc1 = min(max(x1, 0), W_ - 1);
        s_w[0][k][p] = (vy0 && vx0) ? hy * hx : 0.0f;
        s_w[1][k][p] = (vy0 && vx1) ? hy * lx : 0.0f;
        s_w[2][k][p] = (vy1 && vx0) ? ly * hx : 0.0f;
        s_w[3][k][p] = (vy1 && vx1) ? ly * lx : 0.0f;
        s_idx[0][k][p] = yc0 * W_ + xc0;
        s_idx[1][k][p] = yc0 * W_ + xc1;
        s_idx[2][k][p] = yc1 * W_ + xc0;
        s_idx[3][k][p] = yc1 * W_ + xc1;
    }
    __syncthreads();

    // ---- Phase 2: K-loop (9 taps x 8 chunks of 32 channels) ---------------
    const int o0 = (tid >> 2) * 2;        // 0..254, step 2
    const int p0 = (tid & 3) * 16;        // 0,16,32,48
    const int ps = tid & 63;              // staging column
    const int cbase = tid >> 6;           // staging cc base (wave id)

    float4 acc[2][4];
    #pragma unroll
    for (int oo = 0; oo < 2; ++oo)
        #pragma unroll
        for (int q = 0; q < 4; ++q)
            acc[oo][q] = make_float4(0.f, 0.f, 0.f, 0.f);

    for (int k = 0; k < K2_; ++k) {
        // hoist this thread's staging metadata for tap k
        const float mw0 = s_w[0][k][ps], mw1 = s_w[1][k][ps];
        const float mw2 = s_w[2][k][ps], mw3 = s_w[3][k][ps];
        const int   mi0 = s_idx[0][k][ps], mi1 = s_idx[1][k][ps];
        const int   mi2 = s_idx[2][k][ps], mi3 = s_idx[3][k][ps];

        for (int ch = 0; ch < 8; ++ch) {
            __syncthreads();   // previous compute done before col overwrite
            // stage col[32][64]: 4 elements per thread, lanes -> consecutive wo
            #pragma unroll
            for (int i = 0; i < 4; ++i) {
                const int cc = i * 8 + cbase;
                const int c  = ch * 32 + cc;
                const float* plane = x + (size_t)(b * C_ + c) * (H_ * W_);
                const float v = mw0 * plane[mi0] + mw1 * plane[mi1]
                              + mw2 * plane[mi2] + mw3 * plane[mi3];
                s_col[cc][ps] = v;
            }
            __syncthreads();
            // compute: 2 o x 16 p per thread
            #pragma unroll 4
            for (int cc = 0; cc < 32; ++cc) {
                const int c = ch * 32 + cc;
                float2 wv;
                if (use_wt) {
                    wv = *reinterpret_cast<const float2*>(
                        &wsrc[((k * C_ + c) << 8) + o0]);
                } else {
                    wv.x = wsrc[((o0    ) * C_ + c) * K2_ + k];
                    wv.y = wsrc[((o0 + 1) * C_ + c) * K2_ + k];
                }
                const float4* col4 =
                    reinterpret_cast<const float4*>(&s_col[cc][p0]);
                #pragma unroll
                for (int q = 0; q < 4; ++q) {
                    const float4 cv = col4[q];
                    acc[0][q].x += wv.x * cv.x;
                    acc[0][q].y += wv.x * cv.y;
                    acc[0][q].z += wv.x * cv.z;
                    acc[0][q].w += wv.x * cv.w;
                    acc[1][q].x += wv.y * cv.x;
                    acc[1][q].y += wv.y * cv.y;
                    acc[1][q].z += wv.y * cv.z;
                    acc[1][q].w += wv.y * cv.w;
                }
            }
        }
    }

    // ---- Epilogue ----------------------------------------------------------
    #pragma unroll
    for (int oo = 0; oo < 2; ++oo) {
        float* orow = out + (((size_t)(b * CO_ + o0 + oo) * 64 + ho) * 64 + p0);
        #pragma unroll
        for (int q = 0; q < 4; ++q) {
            *reinterpret_cast<float4*>(orow + 4 * q) = acc[oo][q];
        }
    }
}

// ---------------------------------------------------------------------------
extern "C" void kernel_launch(void* const* d_in, const int* in_sizes, int n_in,
                              void* d_out, int out_size, void* d_ws, size_t ws_size,
                              hipStream_t stream) {
    const float* x      = (const float*)d_in[0];
    const float* offset = (const float*)d_in[1];
    const float* weight = (const float*)d_in[2];
    float* out = (float*)d_out;

    const size_t wt_bytes = (size_t)K2_ * C_ * CO_ * sizeof(float);
    const int use_wt = (ws_size >= wt_bytes) ? 1 : 0;
    float* wT = (float*)d_ws;

    if (use_wt) {
        const int n = K2_ * C_ * CO_;
        wtrans_kernel<<<(n + 255) / 256, 256, 0, stream>>>(weight, wT);
    }

    dcn_fwd_kernel<<<B_ * 64, 512, 0, stream>>>(
        x, offset, use_wt ? wT : weight, out, use_wt);
}

// Round 2
// 141.831 us; speedup vs baseline: 2.9507x; 2.9507x over previous
//
#include <hip/hip_runtime.h>
#include <cstddef>

// Problem constants:
//   x      [4, 256, 64, 64] fp32
//   offset [4, 18, 64, 64]  fp32   (dy,dx) per 3x3 tap
//   weight [256, 256, 3, 3] fp32
//   out    [4, 256, 64, 64] fp32
// stride=1, pad=1, dil=1 -> Ho=Wo=64
#define B_    4
#define C_    256
#define H_    64
#define W_    64
#define CO_   256
#define K2_   9
#define NSTEP 72      // K = 9*256 = 2304 = 72 steps of 32

typedef __attribute__((ext_vector_type(8))) short short8;
typedef __attribute__((ext_vector_type(4))) float f32x4;

__device__ __forceinline__ unsigned short f2bf(float f) {
    unsigned int u = __builtin_bit_cast(unsigned int, f);
    u = (u + 0x7fffu + ((u >> 16) & 1u)) >> 16;   // round-to-nearest-even
    return (unsigned short)u;
}

// ---------------------------------------------------------------------------
// weight [Co][C][9] fp32 -> wpk[s][mt][lane][e] bf16, exact MFMA A-fragment
// order: s = K-step (tap*8 + c-chunk), mt = 16-row M tile, lane 0..63, e 0..7.
// A(i,k): i = lane&15, k(within step) = 8*(lane>>4)+e;  c = (s&7)*32 + k,
// tap = s>>3, o = mt*16 + (lane&15).
// ---------------------------------------------------------------------------
__global__ void wpack_kernel(const float* __restrict__ w,
                             unsigned short* __restrict__ wpk) {
    const int idx = blockIdx.x * 256 + threadIdx.x;   // 72*16*64 = 73728
    if (idx >= NSTEP * 16 * 64) return;
    const int lane = idx & 63;
    const int mt   = (idx >> 6) & 15;
    const int s    = idx >> 10;
    const int o    = mt * 16 + (lane & 15);
    const int kk0  = (lane >> 4) << 3;
    const int tap  = s >> 3;
    const int c0   = (s & 7) << 5;
    unsigned short h[8];
#pragma unroll
    for (int e = 0; e < 8; ++e) {
        const int c = c0 + kk0 + e;
        h[e] = f2bf(w[(o * C_ + c) * K2_ + tap]);
    }
    uint4 v;
    v.x = h[0] | ((unsigned)h[1] << 16);
    v.y = h[2] | ((unsigned)h[3] << 16);
    v.z = h[4] | ((unsigned)h[5] << 16);
    v.w = h[6] | ((unsigned)h[7] << 16);
    *reinterpret_cast<uint4*>(&wpk[(size_t)idx * 8]) = v;
}

// ---------------------------------------------------------------------------
// Fused deformable conv, bf16 MFMA implicit GEMM.
// One block per (b, ho): M=256 (all Co) x N=64 (all wo), K=2304.
// 8 waves; wave w owns M rows [32w, 32w+32) as two 16x16 M-tiles x 4 N-tiles.
// ---------------------------------------------------------------------------
__global__ __launch_bounds__(512, 1)
void dcn_mfma_kernel(const float* __restrict__ x,
                     const float* __restrict__ off,
                     const unsigned short* __restrict__ wpk,
                     const float* __restrict__ wraw,
                     float* __restrict__ out,
                     int use_pk) {
    __shared__ float s_w[4][K2_][64];     // corner weights (validity folded)
    __shared__ int   s_idx[4][K2_][64];   // clamped plane indices
    __shared__ __align__(16) unsigned short s_colb[2][2048]; // [buf][nt*512+l*8+e]

    const int tid = threadIdx.x;
    const int bid = blockIdx.x;
    // XCD-aware swizzle: consecutive bids round-robin XCDs (bid&7 ~ xcd).
    // XCD q gets batch q>>1, ho band (q&1)*32..+32 -> ~2.5 MB x-working-set/L2.
    const int xcd  = bid & 7;
    const int slot = bid >> 3;            // 0..31
    const int b  = xcd >> 1;
    const int ho = ((xcd & 1) << 5) | slot;

    // ---- Phase 1: sampling metadata for 9 taps x 64 wo ---------------------
    for (int e = tid; e < K2_ * 64; e += 512) {
        const int k = e >> 6;
        const int p = e & 63;
        const float dy = off[((b * 18 + 2 * k    ) * 64 + ho) * 64 + p];
        const float dx = off[((b * 18 + 2 * k + 1) * 64 + ho) * 64 + p];
        const float py = (float)(ho - 1 + k / 3) + dy;
        const float px = (float)(p  - 1 + k % 3) + dx;
        const float y0f = floorf(py);
        const float x0f = floorf(px);
        const float ly = py - y0f, lx = px - x0f;
        const float hy = 1.0f - ly, hx = 1.0f - lx;
        const int y0 = (int)y0f, x0 = (int)x0f;
        const int y1 = y0 + 1,   x1 = x0 + 1;
        const bool vy0 = (y0 >= 0) & (y0 < H_);
        const bool vy1 = (y1 >= 0) & (y1 < H_);
        const bool vx0 = (x0 >= 0) & (x0 < W_);
        const bool vx1 = (x1 >= 0) & (x1 < W_);
        const int yc0 = min(max(y0, 0), H_ - 1);
        const int yc1 = min(max(y1, 0), H_ - 1);
        const int xc0 = min(max(x0, 0), W_ - 1);
        const int xc1 = min(max(x1, 0), W_ - 1);
        s_w[0][k][p] = (vy0 && vx0) ? hy * hx : 0.0f;
        s_w[1][k][p] = (vy0 && vx1) ? hy * lx : 0.0f;
        s_w[2][k][p] = (vy1 && vx0) ? ly * hx : 0.0f;
        s_w[3][k][p] = (vy1 && vx1) ? ly * lx : 0.0f;
        s_idx[0][k][p] = yc0 * W_ + xc0;
        s_idx[1][k][p] = yc0 * W_ + xc1;
        s_idx[2][k][p] = yc1 * W_ + xc0;
        s_idx[3][k][p] = yc1 * W_ + xc1;
    }
    __syncthreads();

    const int lane = tid & 63;
    const int wave = tid >> 6;
    const int wo   = lane;                // staging column == lane
    // B-fragment LDS slot this thread writes: kk = wave*4+j, j=0..3
    //   l = (wo&15) + 16*(kk>>3) = (wo&15) + 16*(wave>>1), e0 = (wave&1)*4
    const unsigned wr_off = ((unsigned)(wo >> 4) << 9)
                          | ((unsigned)((wo & 15) | ((wave >> 1) << 4)) << 3)
                          | ((unsigned)(wave & 1) << 2);

    const float* xb = x + ((size_t)b * C_ * H_ * W_);

    f32x4 acc[2][4];
#pragma unroll
    for (int m = 0; m < 2; ++m)
#pragma unroll
        for (int nt = 0; nt < 4; ++nt)
            acc[m][nt] = (f32x4)(0.0f);

    // A-frag base pointer (packed path): + s*8192 per step, + m*512 per M tile
    const unsigned short* apk = wpk + ((((size_t)wave << 1) * 64 + lane) << 3);

    // ---- Prologue: stage step 0 into buffer 0 ------------------------------
    {
        const float mw0 = s_w[0][0][wo], mw1 = s_w[1][0][wo],
                    mw2 = s_w[2][0][wo], mw3 = s_w[3][0][wo];
        const int   mi0 = s_idx[0][0][wo], mi1 = s_idx[1][0][wo],
                    mi2 = s_idx[2][0][wo], mi3 = s_idx[3][0][wo];
        const float* p0 = xb + ((size_t)(wave << 2) << 12);  // c = wave*4
        unsigned short h[4];
#pragma unroll
        for (int j = 0; j < 4; ++j) {
            const float* p = p0 + ((size_t)j << 12);
            h[j] = f2bf(mw0 * p[mi0] + mw1 * p[mi1] + mw2 * p[mi2] + mw3 * p[mi3]);
        }
        uint2 pk;
        pk.x = h[0] | ((unsigned)h[1] << 16);
        pk.y = h[2] | ((unsigned)h[3] << 16);
        *reinterpret_cast<uint2*>(&s_colb[0][wr_off]) = pk;
    }
    __syncthreads();

    // ---- Main K loop: 72 steps of K=32 -------------------------------------
    for (int s = 0; s < NSTEP; ++s) {
        const int cur = s & 1;

        // A fragments (2 M-tiles per wave)
        short8 a0, a1;
        if (use_pk) {
            const unsigned short* ap = apk + (size_t)s * 8192;
            a0 = *reinterpret_cast<const short8*>(ap);
            a1 = *reinterpret_cast<const short8*>(ap + 512);
        } else {
            const int tap = s >> 3;
            const int cb  = ((s & 7) << 5) + ((lane >> 4) << 3);
            const int o0  = (wave << 5) + (lane & 15);
#pragma unroll
            for (int e = 0; e < 8; ++e) {
                const int c = cb + e;
                a0[e] = (short)f2bf(wraw[(o0 * C_ + c) * K2_ + tap]);
                a1[e] = (short)f2bf(wraw[((o0 + 16) * C_ + c) * K2_ + tap]);
            }
        }

        // B fragments from LDS (canonical lane*16B ds_read_b128)
        short8 bf[4];
#pragma unroll
        for (int nt = 0; nt < 4; ++nt)
            bf[nt] = *reinterpret_cast<const short8*>(
                &s_colb[cur][(nt << 9) | (lane << 3)]);

        // Prefetch gathers for step s+1 (issued before MFMA; latency hidden)
        float gg[16];
        float nw0 = 0.f, nw1 = 0.f, nw2 = 0.f, nw3 = 0.f;
        const int nx = s + 1;
        if (nx < NSTEP) {
            const int tap = nx >> 3;
            nw0 = s_w[0][tap][wo]; nw1 = s_w[1][tap][wo];
            nw2 = s_w[2][tap][wo]; nw3 = s_w[3][tap][wo];
            const int ni0 = s_idx[0][tap][wo], ni1 = s_idx[1][tap][wo],
                      ni2 = s_idx[2][tap][wo], ni3 = s_idx[3][tap][wo];
            const float* p0 = xb + ((size_t)(((nx & 7) << 5) + (wave << 2)) << 12);
#pragma unroll
            for (int j = 0; j < 4; ++j) {
                const float* p = p0 + ((size_t)j << 12);
                gg[j * 4 + 0] = p[ni0];
                gg[j * 4 + 1] = p[ni1];
                gg[j * 4 + 2] = p[ni2];
                gg[j * 4 + 3] = p[ni3];
            }
        }

        // MFMA: 2 M-tiles x 4 N-tiles
#pragma unroll
        for (int nt = 0; nt < 4; ++nt)
            acc[0][nt] = __builtin_amdgcn_mfma_f32_16x16x32_bf16(
                a0, bf[nt], acc[0][nt], 0, 0, 0);
#pragma unroll
        for (int nt = 0; nt < 4; ++nt)
            acc[1][nt] = __builtin_amdgcn_mfma_f32_16x16x32_bf16(
                a1, bf[nt], acc[1][nt], 0, 0, 0);

        // Finish staging step s+1 into the other buffer
        if (nx < NSTEP) {
            unsigned short h[4];
#pragma unroll
            for (int j = 0; j < 4; ++j)
                h[j] = f2bf(nw0 * gg[j * 4 + 0] + nw1 * gg[j * 4 + 1]
                          + nw2 * gg[j * 4 + 2] + nw3 * gg[j * 4 + 3]);
            uint2 pk;
            pk.x = h[0] | ((unsigned)h[1] << 16);
            pk.y = h[2] | ((unsigned)h[3] << 16);
            *reinterpret_cast<uint2*>(&s_colb[cur ^ 1][wr_off]) = pk;
        }
        __syncthreads();
    }

    // ---- Epilogue: D(i,j): i = 4*(lane>>4)+r, j = (lane&15) per 16x16 tile --
#pragma unroll
    for (int m = 0; m < 2; ++m) {
        const int o_base = ((wave << 1) + m) * 16 + ((lane >> 4) << 2);
#pragma unroll
        for (int r = 0; r < 4; ++r) {
            const int o = o_base + r;
            float* orow = out + (((size_t)(b * CO_ + o) * 64 + ho) * 64);
#pragma unroll
            for (int nt = 0; nt < 4; ++nt)
                orow[(nt << 4) | (lane & 15)] = acc[m][nt][r];
        }
    }
}

// ---------------------------------------------------------------------------
extern "C" void kernel_launch(void* const* d_in, const int* in_sizes, int n_in,
                              void* d_out, int out_size, void* d_ws, size_t ws_size,
                              hipStream_t stream) {
    const float* x      = (const float*)d_in[0];
    const float* offset = (const float*)d_in[1];
    const float* weight = (const float*)d_in[2];
    float* out = (float*)d_out;

    const size_t pk_bytes = (size_t)NSTEP * 16 * 64 * 8 * 2;  // 1,179,648 B
    const int use_pk = (ws_size >= pk_bytes) ? 1 : 0;
    unsigned short* wpk = (unsigned short*)d_ws;

    if (use_pk) {
        wpack_kernel<<<288, 256, 0, stream>>>(weight, wpk);
    }
    dcn_mfma_kernel<<<256, 512, 0, stream>>>(x, offset, wpk, weight, out, use_pk);
}